// Round 15
// baseline (990.237 us; speedup 1.0000x reference)
//
#include <hip/hip_runtime.h>
#include <hip/hip_bf16.h>

namespace {

constexpr int HD = 128;   // H
constexpr int SB = 1024;  // S
constexpr int BB = 1024;  // B

typedef __attribute__((ext_vector_type(4)))  float          f32x4;
typedef __attribute__((ext_vector_type(8)))  __bf16         bf16x8;
typedef __attribute__((ext_vector_type(8)))  unsigned short u16x8;
typedef __attribute__((ext_vector_type(4)))  unsigned short u16x4;

__device__ __forceinline__ float fast_tanh(float x) {
  float e = __expf(2.0f * x);
  return 1.0f - 2.0f * __builtin_amdgcn_rcpf(e + 1.0f);
}

} // namespace

// One block per batch row b, 8 waves. Wave w, chunk c computes scores for
// s in [c*128 + w*16, +16) over all 128 o's via 16x16x32 bf16 MFMA with
// hi/lo split (3 products ~ fp32). Then block softmax over S.
//
// REGISTER HISTORY (measured): R6/R10/R11 — the 32x32x16 version needed
// ~190 live regs; backend allocated 128 (unified VGPR/AGPR file) under
// every launch-bounds/waves_per_eu hint tried, spilling ~200MB/dispatch
// (WRITE_SIZE 227MB vs 4MB output). Fix is structural: 16x16x32 shape,
// 16 rows/wave/chunk -> A-state 32 regs (k-parallel over lane>>4), acc
// 32 regs (8 o-tiles x f32x4). Live ~105 < 128 -> no spill.
extern "C" __global__ __launch_bounds__(512)
void attn_fused(const float* __restrict__ hidden,
                const float* __restrict__ enc,
                const float* __restrict__ W,
                const float* __restrict__ bias,
                const float* __restrict__ vvec,
                float* __restrict__ out)
{
  __shared__ unsigned short WeHi[HD * HD];  // 32 KB, swizzled row-major bf16
  __shared__ unsigned short WeLo[HD * HD];  // 32 KB
  __shared__ float hid[HD];
  __shared__ float ehb[HD];                 // eh[b,o] + bias[o]
  __shared__ float sc[SB];                  // scores
  __shared__ float red[16];

  const int b    = blockIdx.x;
  const int tid  = threadIdx.x;
  const int lane = tid & 63;
  const int wv   = tid >> 6;   // wave 0..7
  const int l15  = lane & 15;  // A-row / B-col / C-col
  const int hi4  = lane >> 4;  // k-group 0..3

  if (tid < 32)
    ((f32x4*)hid)[tid] = ((const f32x4*)(hidden + (size_t)b * HD))[tid];
  __syncthreads();

  if (tid < HD) {
    // ehb[o] = bias[o] + sum_h hidden[b,h] * W[o,h]   (Wh part, fp32)
    const float* wr = W + (size_t)tid * (2 * HD);
    float acc = bias[tid];
    #pragma unroll
    for (int h = 0; h < HD; h += 4) {
      f32x4 wq = *(const f32x4*)(wr + h);
      acc += hid[h]     * wq[0];
      acc += hid[h + 1] * wq[1];
      acc += hid[h + 2] * wq[2];
      acc += hid[h + 3] * wq[3];
    }
    ehb[tid] = acc;
  } else {
    // We[o,h] = W[o, 128+h] -> bf16 hi/lo into LDS, XOR-swizzled 16B granules
    for (int e = tid - HD; e < (HD * HD / 4); e += 384) {
      const int o  = e >> 5;
      const int h4 = (e & 31) << 2;
      f32x4 x = *(const f32x4*)(W + (size_t)o * (2 * HD) + HD + h4);
      const int g   = (h4 >> 3) ^ (o & 15);
      const int idx = o * HD + g * 8 + (h4 & 7);
      u16x4 hv, lv;
      #pragma unroll
      for (int j = 0; j < 4; ++j) {
        float xx = x[j];
        __bf16 hb = (__bf16)xx;
        float hf = (float)hb;
        __bf16 lb = (__bf16)(xx - hf);
        hv[j] = __builtin_bit_cast(unsigned short, hb);
        lv[j] = __builtin_bit_cast(unsigned short, lb);
      }
      *(u16x4*)&WeHi[idx] = hv;
      *(u16x4*)&WeLo[idx] = lv;
    }
  }
  __syncthreads();

  // per-lane o-constants for 8 o-tiles: o = T*16 + l15
  float vt[8], et[8];
  #pragma unroll
  for (int T = 0; T < 8; ++T) {
    vt[T] = vvec[T * 16 + l15];
    et[T] = ehb[T * 16 + l15];
  }

  for (int c = 0; c < 8; ++c) {
    const int s0 = c * 128 + wv * 16;
    // A source: enc[b, s0+l15, k], k = ks*32 + hi4*8 + 0..7
    const float* ap = enc + ((size_t)b * SB + (s0 + l15)) * HD + hi4 * 8;

    // load + convert the K=128 strip: 32 regs bf16 hi + lo
    bf16x8 ah[4], al[4];
    #pragma unroll
    for (int ks = 0; ks < 4; ++ks) {
      f32x4 r0 = *(const f32x4*)(ap + ks * 32);
      f32x4 r1 = *(const f32x4*)(ap + ks * 32 + 4);
      #pragma unroll
      for (int j = 0; j < 8; ++j) {
        float xx = (j < 4) ? r0[j] : r1[j - 4];
        __bf16 hb = (__bf16)xx;
        ah[ks][j] = hb;
        al[ks][j] = (__bf16)(xx - (float)hb);
      }
    }

    f32x4 acc[8] = {};

    #pragma unroll
    for (int ks = 0; ks < 4; ++ks) {
      const int slot = (((ks * 4 + hi4) ^ l15)) * 8;  // granule XOR swizzle
      #pragma unroll
      for (int T = 0; T < 8; ++T) {
        const int bi = (T * 16 + l15) * HD + slot;
        bf16x8 bh = __builtin_bit_cast(bf16x8, *(const u16x8*)&WeHi[bi]);
        bf16x8 bl = __builtin_bit_cast(bf16x8, *(const u16x8*)&WeLo[bi]);
        acc[T] = __builtin_amdgcn_mfma_f32_16x16x32_bf16(ah[ks], bh, acc[T], 0, 0, 0);
        acc[T] = __builtin_amdgcn_mfma_f32_16x16x32_bf16(al[ks], bh, acc[T], 0, 0, 0);
        acc[T] = __builtin_amdgcn_mfma_f32_16x16x32_bf16(ah[ks], bl, acc[T], 0, 0, 0);
      }
    }

    // epilogue: C/D map (m89): col = l15, row = hi4*4 + r
    float ps[4];
    #pragma unroll
    for (int r = 0; r < 4; ++r) {
      float s = 0.0f;
      #pragma unroll
      for (int T = 0; T < 8; ++T)
        s += vt[T] * fast_tanh(acc[T][r] + et[T]);
      ps[r] = s;
    }
    // reduce over the 16 o-lanes (bits 0..3 -> stays within l15 groups)
    #pragma unroll
    for (int d = 1; d <= 8; d <<= 1) {
      #pragma unroll
      for (int r = 0; r < 4; ++r)
        ps[r] += __shfl_xor(ps[r], d, 64);
    }
    if (l15 == 0) {
      #pragma unroll
      for (int r = 0; r < 4; ++r)
        sc[s0 + hi4 * 4 + r] = ps[r];
    }
  }
  __syncthreads();

  // ---- softmax over S = 1024 ----
  const float x0 = sc[tid];
  const float x1 = sc[tid + 512];
  float m = fmaxf(x0, x1);
  #pragma unroll
  for (int d = 32; d >= 1; d >>= 1) m = fmaxf(m, __shfl_xor(m, d, 64));
  if (lane == 0) red[wv] = m;
  __syncthreads();
  float M = red[0];
  #pragma unroll
  for (int i = 1; i < 8; ++i) M = fmaxf(M, red[i]);
  const float e0 = __expf(x0 - M);
  const float e1 = __expf(x1 - M);
  float s2 = e0 + e1;
  #pragma unroll
  for (int d = 32; d >= 1; d >>= 1) s2 += __shfl_xor(s2, d, 64);
  if (lane == 0) red[8 + wv] = s2;
  __syncthreads();
  float T = 0.0f;
  #pragma unroll
  for (int i = 0; i < 8; ++i) T += red[8 + i];
  const float inv = 1.0f / T;
  out[(size_t)b * SB + tid]       = e0 * inv;
  out[(size_t)b * SB + 512 + tid] = e1 * inv;
}

extern "C" void kernel_launch(void* const* d_in, const int* in_sizes, int n_in,
                              void* d_out, int out_size, void* d_ws, size_t ws_size,
                              hipStream_t stream) {
  const float* hidden = (const float*)d_in[0];
  const float* enc    = (const float*)d_in[1];
  const float* W      = (const float*)d_in[2];
  const float* bias   = (const float*)d_in[3];
  const float* vvec   = (const float*)d_in[4];
  float* out = (float*)d_out;
  (void)in_sizes; (void)n_in; (void)out_size; (void)d_ws; (void)ws_size;
  attn_fused<<<dim3(BB), dim3(512), 0, stream>>>(hidden, enc, W, bias, vvec, out);
}